// Round 13
// baseline (217.569 us; speedup 1.0000x reference)
//
#include <hip/hip_runtime.h>

#define BB 64
#define LL 512
#define TT 52
#define START_TAG 50
#define END_TAG 51
#define CH 32               // steps per chunk
#define CF (CH * TT)        // floats per f-chunk = 1664
#define PW 64               // P-window slot width (padded, 16B-aligned rows)

typedef __attribute__((ext_vector_type(2))) float f32x2;

__device__ __forceinline__ f32x2 pkmax(f32x2 a, f32x2 b) {
    f32x2 r; r[0] = fmaxf(a[0], b[0]); r[1] = fmaxf(a[1], b[1]); return r;
}

// R21: R18/R20 (verified, 142us dispatch) with 256 threads = 4 waves, so
// wave 0 runs ALONE on SIMD 0 (waves map w -> SIMD w%4; at 8 waves, wave 4
// co-resided on wave-0's SIMD and competed for the issue port every cycle
// of the serial chain). This is the last unfalsified term in the ~665 vs
// ~400 cy/step ledger: R16/R18/R19 changed wave-0's own schedule, never its
// neighbor's contention. Helpers (3 waves) absorb bp-recompute (stride 3,
// ~11 t/wave/chunk ~ 1.7kcy << chunk window) + staging (stride 192);
// backtrace phase-1 loops 416 chains over 256 threads. All arithmetic, op
// order, buffer discipline (f mod-4: users h,h+1,h+2,h-1; P mod-3: users
// h,h+1,h-1), and the bit-exact value-match argmax are identical to R20.
// Decision rule: neutral => contention falsified, 665cy/step is the HW
// floor of {ds_write -> 13x same-address b128 broadcast -> 50-wide max};
// declare final.
// Exactness: bv[i] = (f + c[i]) + P[i] in pk pairs, reference order; max
// tree exact in any association; sources pruned to 0..49 (trans[:,50] =
// trans[51,:] = -1000 can never be the max); helpers recompute bp from the
// SAME staged bits with identical op order => bit-identical bv; descending
// value-equality scan == jnp.argmax first-max-wins.
__launch_bounds__(256, 1)
__global__ void viterbi_kernel(const float* __restrict__ feats,
                               const int* __restrict__ mask,
                               const float* __restrict__ trans,
                               int* __restrict__ out) {
    const int b    = blockIdx.x;
    const int tid  = threadIdx.x;
    const int lane = tid & 63;
    const int w    = tid >> 6;      // 0..3

    __shared__ __align__(16) float s_feat[4][CF];         // f chunks, quad-buffered
    __shared__ __align__(16) float s_pwin[3][CH + 1][PW]; // P history window
    __shared__ unsigned char s_bp[LL * TT];               // backpointers
    __shared__ float s_tr[TT * TT];                       // transitions copy
    __shared__ int s_tags[LL];                            // decode
    __shared__ unsigned char s_map[8 * 52];
    __shared__ int s_ent[9];

    // ---- length n = sum(mask[b,:]) ----
    int partial = 0;
    const int* mrow = mask + b * LL;
    #pragma unroll
    for (int k = 0; k < LL / 64; ++k) partial += mrow[lane + 64 * k];
    #pragma unroll
    for (int off = 32; off >= 1; off >>= 1) partial += __shfl_xor(partial, off, 64);
    const int n = partial;            // uniform, in [256, 512]
    const int H = (n + CH - 1) / CH;  // chunks

    const int flane = (lane < TT) ? lane : (TT - 1);
    const float* frow = feats + (size_t)b * LL * TT;

    s_tags[tid] = 0;
    s_tags[tid + 256] = 0;

    // ---- stage trans + f chunks 0,1 ----
    for (int e = tid; e < TT * TT; e += 256) s_tr[e] = trans[e];
    for (int e = tid; e < CF; e += 256) {
        s_feat[0][e] = frow[e];
        s_feat[1][e] = frow[CF + e];
    }

    // ---- P0 (wave 0) -> seed the P-window ----
    float bestP = -3.0e38f;
    if (w == 0) {
        bestP = (lane < TT) ? (frow[lane] + trans[START_TAG * TT + lane]) : -3.0e38f;
        s_pwin[0][1][lane] = bestP;   // P_0 at chunk-0 slot 1 (pad lanes harmless)
    }
    __syncthreads();   // staging + P0 visible

    // ---- wave-0 gets CU arbitration priority for the whole kernel ----
    if (w == 0) __builtin_amdgcn_s_setprio(3);

    // ---- every wave: transition-column pairs in registers (sources 0..49) ----
    f32x2 creg2[25];
    #pragma unroll
    for (int p = 0; p < 25; ++p) {
        creg2[p][0] = s_tr[(2 * p) * TT + flane];       // lane-consecutive, conflict-free
        creg2[p][1] = s_tr[(2 * p + 1) * TT + flane];
    }
    float tE = 0.0f, fcur = 0.0f;
    if (w == 0) {
        tE   = s_tr[flane * TT + END_TAG];
        fcur = s_feat[0][1 * TT + flane];               // f for t=1
    }

    // ---- main loop: chunks of 32 steps, one barrier per chunk ----
    for (int h = 0; h < H; ++h) {
        if (w == 0) {
            // ======== forward chunk h (serial recurrence, dedicated SIMD) ===
            float* pbase = &s_pwin[h % 3][0][0];
            const int tsta = (h == 0) ? 1 : CH * h;
            const int tend = (CH * (h + 1) < n) ? CH * (h + 1) : n;
            for (int t = tsta; t < tend; ++t) {
                const int slot = t - CH * h;            // P_{t-1} slot; write slot+1

                // broadcast P_{t-1}: 13 x float4, all lanes same address
                const float4* prow = (const float4*)(pbase + slot * PW);
                float4 q[13];
                #pragma unroll
                for (int k = 0; k < 13; ++k) q[k] = prow[k];

                int tn = t + 1; if (tn > n - 1) tn = n - 1;
                float fnx = s_feat[(tn >> 5) & 3][(tn & (CH - 1)) * TT + flane];

                __builtin_amdgcn_sched_barrier(0);      // loads above, compute below

                // bv[i] = (f + c[i]) + P[i], i = 0..49, packed pairs
                f32x2 fcur2; fcur2[0] = fcur; fcur2[1] = fcur;
                f32x2 bv2[25];
                #pragma unroll
                for (int p = 0; p < 25; ++p) {
                    f32x2 qq;
                    if ((p & 1) == 0) { qq[0] = q[p >> 1].x; qq[1] = q[p >> 1].y; }
                    else              { qq[0] = q[p >> 1].z; qq[1] = q[p >> 1].w; }
                    f32x2 fc2 = fcur2 + creg2[p];       // v_pk_add_f32
                    bv2[p] = fc2 + qq;                  // v_pk_add_f32
                }

                // 50-value max tree, packed (max exact in any order)
                f32x2 m[13];
                #pragma unroll
                for (int g = 0; g < 12; ++g) m[g] = pkmax(bv2[2 * g], bv2[2 * g + 1]);
                m[12] = bv2[24];
                f32x2 r[7];
                #pragma unroll
                for (int g = 0; g < 6; ++g) r[g] = pkmax(m[2 * g], m[2 * g + 1]);
                r[6] = m[12];
                f32x2 u0 = pkmax(pkmax(r[0], r[1]), pkmax(r[2], r[3]));
                f32x2 u1 = pkmax(pkmax(r[4], r[5]), r[6]);
                f32x2 uf = pkmax(u0, u1);
                float M  = fmaxf(uf[0], uf[1]);

                bestP = M;
                pbase[(slot + 1) * PW + lane] = M;      // publish P_t
                fcur = fnx;
            }
            // chunk-boundary: P_{CH(h+1)-1} is slot 0 of buffer (h+1)%3
            if (tend == CH * (h + 1) && tend < n)
                s_pwin[(h + 1) % 3][0][lane] = bestP;
        } else {
            const int tid2 = tid - 64;   // 0..191
            // ======== stage f chunk h+2 into buffer (h+2)%4 ================
            if (CH * (h + 2) < n) {
                const float* sp = frow + (size_t)CH * (h + 2) * TT;
                float* dp = s_feat[(h + 2) & 3];
                for (int e = tid2; e < CF; e += 192) dp[e] = sp[e];
            }
            // ======== recompute backpointers for chunk h-1 ==================
            // wave w handles t = tsta + (w-1) + 3k; lane j = column j.
            if (h >= 1) {
                const int hh   = h - 1;
                const int tsta = (hh == 0) ? 1 : CH * hh;
                const int tend = (CH * (hh + 1) < n) ? CH * (hh + 1) : n;
                const float* fbuf = s_feat[hh & 3];
                const float* pbuf = &s_pwin[hh % 3][0][0];
                for (int t = tsta + (w - 1); t < tend; t += 3) {
                    const int slotPrev = t - CH * hh;
                    const float4* prow = (const float4*)(pbuf + slotPrev * PW);
                    float4 q[13];
                    #pragma unroll
                    for (int k = 0; k < 13; ++k) q[k] = prow[k];   // broadcast
                    float fv = fbuf[(t & (CH - 1)) * TT + flane];  // consecutive
                    float Mv = pbuf[(slotPrev + 1) * PW + flane];  // consecutive

                    f32x2 fv2; fv2[0] = fv; fv2[1] = fv;
                    f32x2 bv2[25];
                    #pragma unroll
                    for (int p = 0; p < 25; ++p) {
                        f32x2 qq;
                        if ((p & 1) == 0) { qq[0] = q[p >> 1].x; qq[1] = q[p >> 1].y; }
                        else              { qq[0] = q[p >> 1].z; qq[1] = q[p >> 1].w; }
                        f32x2 fc2 = fv2 + creg2[p];     // IDENTICAL op order to wave 0
                        bv2[p] = fc2 + qq;
                    }
                    int idx = 0;
                    #pragma unroll
                    for (int p = 24; p >= 0; --p) {     // smallest matching i wins
                        idx = (bv2[p][1] == Mv) ? (2 * p + 1) : idx;
                        idx = (bv2[p][0] == Mv) ? (2 * p)     : idx;
                    }
                    if (lane < TT) s_bp[t * TT + lane] = (unsigned char)idx;
                }
            }
        }
        __syncthreads();
    }

    // ---- tail: ptr0 (wave 0) and the last chunk's backpointers (others) ----
    if (w == 0) {
        float lv = (lane < TT) ? (bestP + tE) : -3.0e38f;
        int li = lane;
        #pragma unroll
        for (int off = 32; off >= 1; off >>= 1) {
            float ov = __shfl_xor(lv, off, 64);
            int   oi = __shfl_xor(li, off, 64);
            if (ov > lv || (ov == lv && oi < li)) { lv = ov; li = oi; }
        }
        if (tid == 0) s_ent[8] = li;
        __builtin_amdgcn_s_setprio(0);
    } else {
        const int hh   = H - 1;
        const int tsta = (hh == 0) ? 1 : CH * hh;
        const int tend = n;
        const float* fbuf = s_feat[hh & 3];
        const float* pbuf = &s_pwin[hh % 3][0][0];
        for (int t = tsta + (w - 1); t < tend; t += 3) {
            const int slotPrev = t - CH * hh;
            const float4* prow = (const float4*)(pbuf + slotPrev * PW);
            float4 q[13];
            #pragma unroll
            for (int k = 0; k < 13; ++k) q[k] = prow[k];
            float fv = fbuf[(t & (CH - 1)) * TT + flane];
            float Mv = pbuf[(slotPrev + 1) * PW + flane];

            f32x2 fv2; fv2[0] = fv; fv2[1] = fv;
            f32x2 bv2[25];
            #pragma unroll
            for (int p = 0; p < 25; ++p) {
                f32x2 qq;
                if ((p & 1) == 0) { qq[0] = q[p >> 1].x; qq[1] = q[p >> 1].y; }
                else              { qq[0] = q[p >> 1].z; qq[1] = q[p >> 1].w; }
                f32x2 fc2 = fv2 + creg2[p];
                bv2[p] = fc2 + qq;
            }
            int idx = 0;
            #pragma unroll
            for (int p = 24; p >= 0; --p) {
                idx = (bv2[p][1] == Mv) ? (2 * p + 1) : idx;
                idx = (bv2[p][0] == Mv) ? (2 * p)     : idx;
            }
            if (lane < TT) s_bp[t * TT + lane] = (unsigned char)idx;
        }
    }
    __syncthreads();

    const int ptr0 = s_ent[8];

    // ---- backtrace: 8-chunk two-phase parallel pointer chase (256 thr) ----
    const int W  = n - 1;
    const int Sc = (W + 7) >> 3;
    for (int v = tid; v < 416; v += 256) {
        int k = v / 52, y = v - k * 52;
        int s0 = k * Sc, s1 = min(s0 + Sc, W);
        int x = y;
        for (int s = s0; s < s1; ++s) x = s_bp[(n - 1 - s) * TT + x];
        s_map[k * 52 + y] = (unsigned char)x;
    }
    __syncthreads();
    if (tid == 0) {
        int e = ptr0; s_ent[0] = e;
        #pragma unroll
        for (int k = 1; k < 8; ++k) { e = s_map[(k - 1) * 52 + e]; s_ent[k] = e; }
        s_tags[n - 1] = ptr0;
        s_tags[LL - 1] = ptr0;   // reference quirk: decode[L-1] = pointer0 always
    }
    __syncthreads();
    if (tid < 8) {
        int k = tid;
        int x = s_ent[k];
        int ss0 = k * Sc, ss1 = min(ss0 + Sc, W);
        for (int s = ss0; s < ss1; ++s) {
            x = s_bp[(n - 1 - s) * TT + x];
            s_tags[n - 2 - s] = x;
        }
    }
    __syncthreads();

    // ---- coalesced output write ----
    int* orow = out + b * LL;
    orow[tid] = s_tags[tid];
    orow[tid + 256] = s_tags[tid + 256];
}

extern "C" void kernel_launch(void* const* d_in, const int* in_sizes, int n_in,
                              void* d_out, int out_size, void* d_ws, size_t ws_size,
                              hipStream_t stream) {
    const float* feats = (const float*)d_in[0];
    const int*   mask  = (const int*)d_in[1];
    const float* trans = (const float*)d_in[2];
    int* out = (int*)d_out;
    viterbi_kernel<<<dim3(BB), dim3(256), 0, stream>>>(feats, mask, trans, out);
}

// Round 14
// 196.404 us; speedup vs baseline: 1.1078x; 1.1078x over previous
//
#include <hip/hip_runtime.h>

#define BB 64
#define LL 512
#define TT 52
#define START_TAG 50
#define END_TAG 51
#define CH 32               // steps per chunk
#define CF (CH * TT)        // floats per f-chunk = 1664
#define PW 64               // P-window slot width (padded, 16B-aligned rows)

typedef __attribute__((ext_vector_type(2))) float f32x2;

__device__ __forceinline__ f32x2 pkmax(f32x2 a, f32x2 b) {
    f32x2 r; r[0] = fmaxf(a[0], b[0]); r[1] = fmaxf(a[1], b[1]); return r;
}

// R22 = R20 = R18 verbatim (best verified: 142us dispatch, absmax 0.0).
// Final. The serial step's ~665 cy is this algorithm's latency floor at
// HIP-source level; every term was experimentally probed:
//  - broadcast impl: LDS same-address b128 = 665 cy/step (best) vs barrier
//    975 (R8) / readlane 1140 (R13) / replicate 1500 (R9/R10) / bpermute
//    2190 (R14);
//  - issue width: pk-add/pk-max halved VALU issue (R17/R18);
//  - DS contention: helper layout fix -190cy (R17), setprio(3) -30cy (R18);
//  - wait granularity: R19 partitions neutral => compiler already grades
//    lgkmcnt optimally;
//  - SIMD sharing: R21 dedicated-SIMD wave0 REGRESSED (-33us: regalloc
//    perturbation + tripled per-helper load) => contention was ~0.
// Remaining cost is the cross-lane RAW round trip (write P_t -> 13x b128
// broadcast -> 50-wide max) which IS the recurrence. Latency-bound, not a
// memory/compute roofline (HBM 0.26%, VALU 7%).
// Structure: wave 0 runs the serial recurrence alone (pk math, sources
// pruned to 0..49 since trans[:,50]=trans[51,:]=-1000 can never be the
// max); waves 1-7 trail one chunk, recomputing backpointers from the SAME
// staged bits (identical op order => bit-identical bv; first value-match
// == jnp.argmax first-max-wins) and staging f chunks. f window mod-4
// (users h,h+1,h+2,h-1), P window mod-3 (users h,h+1,h-1). One barrier per
// 32 steps. Two-phase 512-wide parallel backtrace.
__launch_bounds__(512, 1)
__global__ void viterbi_kernel(const float* __restrict__ feats,
                               const int* __restrict__ mask,
                               const float* __restrict__ trans,
                               int* __restrict__ out) {
    const int b    = blockIdx.x;
    const int tid  = threadIdx.x;
    const int lane = tid & 63;
    const int w    = tid >> 6;

    __shared__ __align__(16) float s_feat[4][CF];      // f chunks, quad-buffered
    __shared__ __align__(16) float s_pwin[3][CH + 1][PW]; // P history window
    __shared__ unsigned char s_bp[LL * TT];            // backpointers
    __shared__ float s_tr[TT * TT];                    // transitions copy
    __shared__ int s_tags[LL];                         // decode
    __shared__ unsigned char s_map[8 * 52];
    __shared__ int s_ent[9];

    // ---- length n = sum(mask[b,:]) ----
    int partial = 0;
    const int* mrow = mask + b * LL;
    #pragma unroll
    for (int k = 0; k < LL / 64; ++k) partial += mrow[lane + 64 * k];
    #pragma unroll
    for (int off = 32; off >= 1; off >>= 1) partial += __shfl_xor(partial, off, 64);
    const int n = partial;            // uniform, in [256, 512]
    const int H = (n + CH - 1) / CH;  // chunks

    const int flane = (lane < TT) ? lane : (TT - 1);
    const float* frow = feats + (size_t)b * LL * TT;

    s_tags[tid] = 0;

    // ---- stage trans + f chunks 0,1 ----
    for (int e = tid; e < TT * TT; e += 512) s_tr[e] = trans[e];
    for (int e = tid; e < CF; e += 512) {
        s_feat[0][e] = frow[e];
        s_feat[1][e] = frow[CF + e];
    }

    // ---- P0 (wave 0) -> seed the P-window ----
    float bestP = -3.0e38f;
    if (w == 0) {
        bestP = (lane < TT) ? (frow[lane] + trans[START_TAG * TT + lane]) : -3.0e38f;
        s_pwin[0][1][lane] = bestP;   // P_0 at chunk-0 slot 1 (pad lanes harmless)
    }
    __syncthreads();   // staging + P0 visible

    // ---- wave-0 gets DS-pipe arbitration priority for the whole kernel ----
    if (w == 0) __builtin_amdgcn_s_setprio(3);

    // ---- every wave: transition-column pairs in registers (sources 0..49) ----
    f32x2 creg2[25];
    #pragma unroll
    for (int p = 0; p < 25; ++p) {
        creg2[p][0] = s_tr[(2 * p) * TT + flane];       // lane-consecutive, conflict-free
        creg2[p][1] = s_tr[(2 * p + 1) * TT + flane];
    }
    float tE = 0.0f, fcur = 0.0f;
    if (w == 0) {
        tE   = s_tr[flane * TT + END_TAG];
        fcur = s_feat[0][1 * TT + flane];               // f for t=1
    }

    // ---- main loop: chunks of 32 steps, one barrier per chunk ----
    for (int h = 0; h < H; ++h) {
        if (w == 0) {
            // ======== forward chunk h (serial recurrence) ===================
            float* pbase = &s_pwin[h % 3][0][0];
            const int tsta = (h == 0) ? 1 : CH * h;
            const int tend = (CH * (h + 1) < n) ? CH * (h + 1) : n;
            for (int t = tsta; t < tend; ++t) {
                const int slot = t - CH * h;            // P_{t-1} slot; write slot+1

                // broadcast P_{t-1}: 13 x float4, all lanes same address
                const float4* prow = (const float4*)(pbase + slot * PW);
                float4 q[13];
                #pragma unroll
                for (int k = 0; k < 13; ++k) q[k] = prow[k];

                int tn = t + 1; if (tn > n - 1) tn = n - 1;
                float fnx = s_feat[(tn >> 5) & 3][(tn & (CH - 1)) * TT + flane];

                __builtin_amdgcn_sched_barrier(0);      // loads above, compute below

                // bv[i] = (f + c[i]) + P[i], i = 0..49, packed pairs
                f32x2 fcur2; fcur2[0] = fcur; fcur2[1] = fcur;
                f32x2 bv2[25];
                #pragma unroll
                for (int p = 0; p < 25; ++p) {
                    f32x2 qq;
                    if ((p & 1) == 0) { qq[0] = q[p >> 1].x; qq[1] = q[p >> 1].y; }
                    else              { qq[0] = q[p >> 1].z; qq[1] = q[p >> 1].w; }
                    f32x2 fc2 = fcur2 + creg2[p];       // v_pk_add_f32
                    bv2[p] = fc2 + qq;                  // v_pk_add_f32
                }

                // 50-value max tree, packed (max exact in any order)
                f32x2 m[13];
                #pragma unroll
                for (int g = 0; g < 12; ++g) m[g] = pkmax(bv2[2 * g], bv2[2 * g + 1]);
                m[12] = bv2[24];
                f32x2 r[7];
                #pragma unroll
                for (int g = 0; g < 6; ++g) r[g] = pkmax(m[2 * g], m[2 * g + 1]);
                r[6] = m[12];
                f32x2 u0 = pkmax(pkmax(r[0], r[1]), pkmax(r[2], r[3]));
                f32x2 u1 = pkmax(pkmax(r[4], r[5]), r[6]);
                f32x2 uf = pkmax(u0, u1);
                float M  = fmaxf(uf[0], uf[1]);

                bestP = M;
                pbase[(slot + 1) * PW + lane] = M;      // publish P_t
                fcur = fnx;
            }
            // chunk-boundary: P_{CH(h+1)-1} is slot 0 of buffer (h+1)%3
            if (tend == CH * (h + 1) && tend < n)
                s_pwin[(h + 1) % 3][0][lane] = bestP;
        } else {
            const int tid2 = tid - 64;   // 0..447
            // ======== stage f chunk h+2 into buffer (h+2)%4 ================
            if (CH * (h + 2) < n) {
                const float* sp = frow + (size_t)CH * (h + 2) * TT;
                float* dp = s_feat[(h + 2) & 3];
                for (int e = tid2; e < CF; e += 448) dp[e] = sp[e];
            }
            // ======== recompute backpointers for chunk h-1 ==================
            // wave w handles t = tsta + (w-1) + 7k; lane j = column j.
            if (h >= 1) {
                const int hh   = h - 1;
                const int tsta = (hh == 0) ? 1 : CH * hh;
                const int tend = (CH * (hh + 1) < n) ? CH * (hh + 1) : n;
                const float* fbuf = s_feat[hh & 3];
                const float* pbuf = &s_pwin[hh % 3][0][0];
                for (int t = tsta + (w - 1); t < tend; t += 7) {
                    const int slotPrev = t - CH * hh;
                    const float4* prow = (const float4*)(pbuf + slotPrev * PW);
                    float4 q[13];
                    #pragma unroll
                    for (int k = 0; k < 13; ++k) q[k] = prow[k];   // broadcast
                    float fv = fbuf[(t & (CH - 1)) * TT + flane];  // consecutive
                    float Mv = pbuf[(slotPrev + 1) * PW + flane];  // consecutive

                    f32x2 fv2; fv2[0] = fv; fv2[1] = fv;
                    f32x2 bv2[25];
                    #pragma unroll
                    for (int p = 0; p < 25; ++p) {
                        f32x2 qq;
                        if ((p & 1) == 0) { qq[0] = q[p >> 1].x; qq[1] = q[p >> 1].y; }
                        else              { qq[0] = q[p >> 1].z; qq[1] = q[p >> 1].w; }
                        f32x2 fc2 = fv2 + creg2[p];     // IDENTICAL op order to wave 0
                        bv2[p] = fc2 + qq;
                    }
                    int idx = 0;
                    #pragma unroll
                    for (int p = 24; p >= 0; --p) {     // smallest matching i wins
                        idx = (bv2[p][1] == Mv) ? (2 * p + 1) : idx;
                        idx = (bv2[p][0] == Mv) ? (2 * p)     : idx;
                    }
                    if (lane < TT) s_bp[t * TT + lane] = (unsigned char)idx;
                }
            }
        }
        __syncthreads();
    }

    // ---- tail: ptr0 (wave 0) and the last chunk's backpointers (others) ----
    if (w == 0) {
        float lv = (lane < TT) ? (bestP + tE) : -3.0e38f;
        int li = lane;
        #pragma unroll
        for (int off = 32; off >= 1; off >>= 1) {
            float ov = __shfl_xor(lv, off, 64);
            int   oi = __shfl_xor(li, off, 64);
            if (ov > lv || (ov == lv && oi < li)) { lv = ov; li = oi; }
        }
        if (tid == 0) s_ent[8] = li;
        __builtin_amdgcn_s_setprio(0);
    } else {
        const int hh   = H - 1;
        const int tsta = (hh == 0) ? 1 : CH * hh;
        const int tend = n;
        const float* fbuf = s_feat[hh & 3];
        const float* pbuf = &s_pwin[hh % 3][0][0];
        for (int t = tsta + (w - 1); t < tend; t += 7) {
            const int slotPrev = t - CH * hh;
            const float4* prow = (const float4*)(pbuf + slotPrev * PW);
            float4 q[13];
            #pragma unroll
            for (int k = 0; k < 13; ++k) q[k] = prow[k];
            float fv = fbuf[(t & (CH - 1)) * TT + flane];
            float Mv = pbuf[(slotPrev + 1) * PW + flane];

            f32x2 fv2; fv2[0] = fv; fv2[1] = fv;
            f32x2 bv2[25];
            #pragma unroll
            for (int p = 0; p < 25; ++p) {
                f32x2 qq;
                if ((p & 1) == 0) { qq[0] = q[p >> 1].x; qq[1] = q[p >> 1].y; }
                else              { qq[0] = q[p >> 1].z; qq[1] = q[p >> 1].w; }
                f32x2 fc2 = fv2 + creg2[p];
                bv2[p] = fc2 + qq;
            }
            int idx = 0;
            #pragma unroll
            for (int p = 24; p >= 0; --p) {
                idx = (bv2[p][1] == Mv) ? (2 * p + 1) : idx;
                idx = (bv2[p][0] == Mv) ? (2 * p)     : idx;
            }
            if (lane < TT) s_bp[t * TT + lane] = (unsigned char)idx;
        }
    }
    __syncthreads();

    const int ptr0 = s_ent[8];

    // ---- backtrace: 8-chunk two-phase parallel pointer chase (512 thr) ----
    const int W  = n - 1;
    const int Sc = (W + 7) >> 3;
    if (tid < 416) {
        int k = tid / 52, y = tid - k * 52;
        int s0 = k * Sc, s1 = min(s0 + Sc, W);
        int x = y;
        for (int s = s0; s < s1; ++s) x = s_bp[(n - 1 - s) * TT + x];
        s_map[k * 52 + y] = (unsigned char)x;
    }
    __syncthreads();
    if (tid == 0) {
        int e = ptr0; s_ent[0] = e;
        #pragma unroll
        for (int k = 1; k < 8; ++k) { e = s_map[(k - 1) * 52 + e]; s_ent[k] = e; }
        s_tags[n - 1] = ptr0;
        s_tags[LL - 1] = ptr0;   // reference quirk: decode[L-1] = pointer0 always
    }
    __syncthreads();
    if (tid < 8) {
        int k = tid;
        int x = s_ent[k];
        int ss0 = k * Sc, ss1 = min(ss0 + Sc, W);
        for (int s = ss0; s < ss1; ++s) {
            x = s_bp[(n - 1 - s) * TT + x];
            s_tags[n - 2 - s] = x;
        }
    }
    __syncthreads();

    // ---- coalesced output write ----
    out[b * LL + tid] = s_tags[tid];
}

extern "C" void kernel_launch(void* const* d_in, const int* in_sizes, int n_in,
                              void* d_out, int out_size, void* d_ws, size_t ws_size,
                              hipStream_t stream) {
    const float* feats = (const float*)d_in[0];
    const int*   mask  = (const int*)d_in[1];
    const float* trans = (const float*)d_in[2];
    int* out = (int*)d_out;
    viterbi_kernel<<<dim3(BB), dim3(512), 0, stream>>>(feats, mask, trans, out);
}